// Round 1
// baseline (4992.813 us; speedup 1.0000x reference)
//
#include <hip/hip_runtime.h>
#include <hip/hip_bf16.h>

#define N_NODES 20000
#define NE      400000
#define HDIM    256

// ---------------------------------------------------------------------------
// PointNet fused edge kernel.
// block 256 threads, 32 edges per block, grid = NE/32 = 12500.
// Computes m = relu(ef @ W1 + b1) @ W2 + b2 per edge, then
// out[dst][co+c] = max over edges (clamped at 0) via u32 atomicMax.
// out must be pre-zeroed; all stored values are >= 0 so uint ordering == float ordering.
// ---------------------------------------------------------------------------
__global__ __launch_bounds__(256) void pointnet_kernel(
    const float* __restrict__ pos, const int* __restrict__ src, const int* __restrict__ dst,
    const float* __restrict__ W1, const float* __restrict__ b1,
    const float* __restrict__ W2, const float* __restrict__ b2,
    float* __restrict__ out, int co)
{
    __shared__ float s_ef[32][8];
    __shared__ int   s_dst[32];
    __shared__ float s_w1[6][256];
    __shared__ float s_b1[256];
    __shared__ float s_b2[256];
    __shared__ float s_hid[256][32];   // hidden, transposed: [k][edge]
    __shared__ float s_w2[32][256];    // K-chunk of W2

    const int t = threadIdx.x;
    const int ebase = blockIdx.x * 32;

    // stage weights
    #pragma unroll
    for (int j = 0; j < 6; ++j) s_w1[j][t] = W1[j * 256 + t];
    s_b1[t] = b1[t];
    s_b2[t] = b2[t];
    if (t < 32) {
        int e = ebase + t;
        int s = src[e], d = dst[e];
        float sx = pos[s * 3 + 0], sy = pos[s * 3 + 1], sz = pos[s * 3 + 2];
        float dx = pos[d * 3 + 0], dy = pos[d * 3 + 1], dz = pos[d * 3 + 2];
        s_ef[t][0] = sx; s_ef[t][1] = sy; s_ef[t][2] = sz;
        s_ef[t][3] = sx - dx; s_ef[t][4] = sy - dy; s_ef[t][5] = sz - dz;
        s_dst[t] = d;
    }
    __syncthreads();

    // phase 1: hidden[k][e] = relu(b1[k] + ef[e] . W1[:,k]); 32 k-values per thread
    {
        int e  = t & 31;
        int k0 = (t >> 5) * 32;
        float f0 = s_ef[e][0], f1 = s_ef[e][1], f2 = s_ef[e][2];
        float f3 = s_ef[e][3], f4 = s_ef[e][4], f5 = s_ef[e][5];
        #pragma unroll 8
        for (int kk = 0; kk < 32; ++kk) {
            int k = k0 + kk;
            float h = s_b1[k];
            h += f0 * s_w1[0][k]; h += f1 * s_w1[1][k]; h += f2 * s_w1[2][k];
            h += f3 * s_w1[3][k]; h += f4 * s_w1[4][k]; h += f5 * s_w1[5][k];
            s_hid[k][e] = fmaxf(h, 0.f);
        }
    }

    // phase 2: m = hidden @ W2; per-thread 4 edges x 8 channels
    const int cg = t & 31;  const int c0 = cg * 8;
    const int eg = t >> 5;  const int e0 = eg * 4;
    float acc[4][8];
    #pragma unroll
    for (int i = 0; i < 4; ++i)
        #pragma unroll
        for (int j = 0; j < 8; ++j) acc[i][j] = 0.f;

    for (int kc = 0; kc < 256; kc += 32) {
        __syncthreads();
        // stage 32x256 chunk of W2 (2048 float4, 8 per thread, coalesced)
        #pragma unroll
        for (int it = 0; it < 8; ++it) {
            int f  = it * 256 + t;
            int r  = f >> 6;
            int c4 = (f & 63) * 4;
            *(float4*)&s_w2[r][c4] = *(const float4*)&W2[(kc + r) * 256 + c4];
        }
        __syncthreads();
        #pragma unroll 4
        for (int kk = 0; kk < 32; ++kk) {
            int k = kc + kk;
            float4 hv = *(const float4*)&s_hid[k][e0];
            float4 wa = *(const float4*)&s_w2[kk][c0];
            float4 wb = *(const float4*)&s_w2[kk][c0 + 4];
            float h_[4] = {hv.x, hv.y, hv.z, hv.w};
            float w_[8] = {wa.x, wa.y, wa.z, wa.w, wb.x, wb.y, wb.z, wb.w};
            #pragma unroll
            for (int i = 0; i < 4; ++i)
                #pragma unroll
                for (int j = 0; j < 8; ++j)
                    acc[i][j] += h_[i] * w_[j];
        }
    }

    // epilogue: add b2, clamp 0, atomicMax into out rows
    #pragma unroll
    for (int i = 0; i < 4; ++i) {
        int d = s_dst[e0 + i];
        unsigned int* orow = (unsigned int*)(out + (size_t)d * 512 + co + c0);
        #pragma unroll
        for (int j = 0; j < 8; ++j) {
            float m = acc[i][j] + s_b2[c0 + j];
            if (m > 0.f) atomicMax(&orow[j], __float_as_uint(m));
        }
    }
}

// ---------------------------------------------------------------------------
// Generic fp32 GEMM: C[:, cco:cco+128] = opt_relu(A[M,K] @ W[K,128] + bias)
// block 256, tile 32 rows x 128 cols, grid = M/32. K % 64 == 0.
// ---------------------------------------------------------------------------
template <int KDIM>
__global__ __launch_bounds__(256) void gemm_kernel(
    const float* __restrict__ A, int lda,
    const float* __restrict__ W,
    const float* __restrict__ bias,
    float* __restrict__ C, int ldc, int cco, int dorelu)
{
    __shared__ float s_a[32][68];    // 32 rows x 64 k (padded, 16B-aligned rows)
    __shared__ float s_w[64][128];

    const int t  = threadIdx.x;
    const int mb = blockIdx.x * 32;
    const int tn = t & 31;  const int c0 = tn * 4;
    const int tm = t >> 5;  const int m0 = tm * 4;

    float acc[4][4];
    #pragma unroll
    for (int i = 0; i < 4; ++i)
        #pragma unroll
        for (int j = 0; j < 4; ++j) acc[i][j] = 0.f;

    for (int kc = 0; kc < KDIM; kc += 64) {
        __syncthreads();
        // stage A tile: 32 rows x 64 k = 512 float4
        #pragma unroll
        for (int it = 0; it < 2; ++it) {
            int f  = it * 256 + t;
            int r  = f >> 4;
            int k4 = (f & 15) * 4;
            *(float4*)&s_a[r][k4] = *(const float4*)&A[(size_t)(mb + r) * lda + kc + k4];
        }
        // stage W chunk: 64 x 128 = 2048 float4
        #pragma unroll
        for (int it = 0; it < 8; ++it) {
            int f  = it * 256 + t;
            int r  = f >> 5;
            int c4 = (f & 31) * 4;
            *(float4*)&s_w[r][c4] = *(const float4*)&W[(size_t)(kc + r) * 128 + c4];
        }
        __syncthreads();
        #pragma unroll 8
        for (int kk = 0; kk < 64; ++kk) {
            float4 wv = *(const float4*)&s_w[kk][c0];
            float av[4];
            #pragma unroll
            for (int i = 0; i < 4; ++i) av[i] = s_a[m0 + i][kk];
            #pragma unroll
            for (int i = 0; i < 4; ++i) {
                acc[i][0] += av[i] * wv.x;
                acc[i][1] += av[i] * wv.y;
                acc[i][2] += av[i] * wv.z;
                acc[i][3] += av[i] * wv.w;
            }
        }
    }

    #pragma unroll
    for (int i = 0; i < 4; ++i) {
        int row = mb + m0 + i;
        float4 v;
        v.x = acc[i][0]; v.y = acc[i][1]; v.z = acc[i][2]; v.w = acc[i][3];
        if (bias) { v.x += bias[c0]; v.y += bias[c0 + 1]; v.z += bias[c0 + 2]; v.w += bias[c0 + 3]; }
        if (dorelu) { v.x = fmaxf(v.x, 0.f); v.y = fmaxf(v.y, 0.f); v.z = fmaxf(v.z, 0.f); v.w = fmaxf(v.w, 0.f); }
        *(float4*)&C[(size_t)row * ldc + cco + c0] = v;
    }
}

// ---------------------------------------------------------------------------
// degree / dinv helpers
// ---------------------------------------------------------------------------
__global__ void fill_deg_kernel(float* deg0, float* deg1) {
    int i = blockIdx.x * blockDim.x + threadIdx.x;
    if (i < N_NODES) { deg0[i] = 1.f; deg1[i] = 1.f; }
}

__global__ void deg_acc_kernel(const int* __restrict__ dst0, float* deg0,
                               const int* __restrict__ dst1, float* deg1) {
    int e = blockIdx.x * blockDim.x + threadIdx.x;
    if (e < NE) {
        unsafeAtomicAdd(&deg0[dst0[e]], 1.f);
        unsafeAtomicAdd(&deg1[dst1[e]], 1.f);
    }
}

__global__ void dinv_kernel(float* deg0, float* deg1) {
    int i = blockIdx.x * blockDim.x + threadIdx.x;
    if (i < N_NODES) { deg0[i] = rsqrtf(deg0[i]); deg1[i] = rsqrtf(deg1[i]); }
}

// ---------------------------------------------------------------------------
// GCN edge scatter: agg[dst] += xw[src] * dinv[src]*dinv[dst]
// block 256 = 8 edges x 32 lanes x 4 channels
// ---------------------------------------------------------------------------
__global__ __launch_bounds__(256) void gcn_scatter_kernel(
    const int* __restrict__ src, const int* __restrict__ dst,
    const float* __restrict__ dinv, const float* __restrict__ xw,
    float* __restrict__ agg)
{
    int t = threadIdx.x;
    int e = blockIdx.x * 8 + (t >> 5);
    int lc = (t & 31) * 4;
    if (e < NE) {
        int s = src[e], d = dst[e];
        float nrm = dinv[s] * dinv[d];
        float4 v = *(const float4*)&xw[(size_t)s * 128 + lc];
        float* ap = &agg[(size_t)d * 128 + lc];
        unsafeAtomicAdd(ap + 0, v.x * nrm);
        unsafeAtomicAdd(ap + 1, v.y * nrm);
        unsafeAtomicAdd(ap + 2, v.z * nrm);
        unsafeAtomicAdd(ap + 3, v.w * nrm);
    }
}

// h2[i][co+c] = relu(agg[i][c] + xw[i][c]/deg[i] + b[c])
__global__ __launch_bounds__(256) void gcn_combine_kernel(
    const float* __restrict__ agg, const float* __restrict__ xw,
    const float* __restrict__ dinv, const float* __restrict__ b,
    float* __restrict__ h2, int co)
{
    int i = blockIdx.x * 2 + (threadIdx.x >> 7);
    int c = threadIdx.x & 127;
    float dv = dinv[i];
    float v = agg[(size_t)i * 128 + c] + xw[(size_t)i * 128 + c] * dv * dv + b[c];
    h2[(size_t)i * 256 + co + c] = fmaxf(v, 0.f);
}

// ---------------------------------------------------------------------------
// Final classifier: out[3] = z_flat @ cls_W + cls_b  (out pre-zeroed)
// ---------------------------------------------------------------------------
__global__ __launch_bounds__(256) void classifier_kernel(
    const float* __restrict__ z, const float* __restrict__ clsW,
    const float* __restrict__ clsb, float* __restrict__ out)
{
    float a0 = 0.f, a1 = 0.f, a2 = 0.f;
    const int total = N_NODES * 128;
    for (int i = blockIdx.x * blockDim.x + threadIdx.x; i < total;
         i += gridDim.x * blockDim.x) {
        float v = z[i];
        a0 += v * clsW[(size_t)i * 3 + 0];
        a1 += v * clsW[(size_t)i * 3 + 1];
        a2 += v * clsW[(size_t)i * 3 + 2];
    }
    #pragma unroll
    for (int off = 32; off > 0; off >>= 1) {
        a0 += __shfl_down(a0, off);
        a1 += __shfl_down(a1, off);
        a2 += __shfl_down(a2, off);
    }
    __shared__ float sred[12];
    int w = threadIdx.x >> 6;
    if ((threadIdx.x & 63) == 0) { sred[w * 3] = a0; sred[w * 3 + 1] = a1; sred[w * 3 + 2] = a2; }
    __syncthreads();
    if (threadIdx.x == 0) {
        float r0 = 0.f, r1 = 0.f, r2 = 0.f;
        #pragma unroll
        for (int q = 0; q < 4; ++q) { r0 += sred[q * 3]; r1 += sred[q * 3 + 1]; r2 += sred[q * 3 + 2]; }
        atomicAdd(&out[0], r0); atomicAdd(&out[1], r1); atomicAdd(&out[2], r2);
    }
    if (blockIdx.x == 0 && threadIdx.x < 3) atomicAdd(&out[threadIdx.x], clsb[threadIdx.x]);
}

// ---------------------------------------------------------------------------
extern "C" void kernel_launch(void* const* d_in, const int* in_sizes, int n_in,
                              void* d_out, int out_size, void* d_ws, size_t ws_size,
                              hipStream_t stream) {
    const float* pos0 = (const float*)d_in[0];
    const float* pos1 = (const float*)d_in[1];
    const int*   ei0  = (const int*)d_in[2];
    const int*   ei1  = (const int*)d_in[3];
    const float* p0W1 = (const float*)d_in[6];
    const float* p0b1 = (const float*)d_in[7];
    const float* p0W2 = (const float*)d_in[8];
    const float* p0b2 = (const float*)d_in[9];
    const float* p1W1 = (const float*)d_in[10];
    const float* p1b1 = (const float*)d_in[11];
    const float* p1W2 = (const float*)d_in[12];
    const float* p1b2 = (const float*)d_in[13];
    const float* g0W  = (const float*)d_in[14];
    const float* g0b  = (const float*)d_in[15];
    const float* g1W  = (const float*)d_in[16];
    const float* g1b  = (const float*)d_in[17];
    const float* c3W  = (const float*)d_in[18];
    const float* c3b  = (const float*)d_in[19];
    const float* clsW = (const float*)d_in[20];
    const float* clsb = (const float*)d_in[21];

    const int* s0 = ei0;       const int* d0 = ei0 + NE;
    const int* s1 = ei1;       const int* d1 = ei1 + NE;

    float* ws = (float*)d_ws;
    float* h    = ws;                      // [N,512]   10,240,000
    float* xw0  = ws + 10240000;           // [N,128]    2,560,000
    float* xw1  = ws + 12800000;           // [N,128]
    float* agg0 = ws + 15360000;           // [N,128]
    float* agg1 = ws + 17920000;           // [N,128]
    float* h2   = ws + 20480000;           // [N,256]    5,120,000
    float* z    = ws + 25600000;           // [N,128]
    float* deg0 = ws + 28160000;           // [N]
    float* deg1 = ws + 28180000;           // [N]

    // zero-init: h (atomicMax target), agg0+agg1 (contiguous), d_out
    hipMemsetAsync(h, 0, (size_t)10240000 * 4, stream);
    hipMemsetAsync(agg0, 0, (size_t)2 * 2560000 * 4, stream);
    hipMemsetAsync(d_out, 0, 3 * sizeof(float), stream);

    fill_deg_kernel<<<(N_NODES + 255) / 256, 256, 0, stream>>>(deg0, deg1);

    // PointNet layers -> h[N, 0:256] and h[N, 256:512]
    pointnet_kernel<<<NE / 32, 256, 0, stream>>>(pos0, s0, d0, p0W1, p0b1, p0W2, p0b2, h, 0);
    pointnet_kernel<<<NE / 32, 256, 0, stream>>>(pos1, s1, d1, p1W1, p1b1, p1W2, p1b2, h, 256);

    // degrees -> dinv
    deg_acc_kernel<<<(NE + 255) / 256, 256, 0, stream>>>(d0, deg0, d1, deg1);
    dinv_kernel<<<(N_NODES + 255) / 256, 256, 0, stream>>>(deg0, deg1);

    // xw = h @ gW   (K=512, no bias/relu)
    gemm_kernel<512><<<N_NODES / 32, 256, 0, stream>>>(h, 512, g0W, nullptr, xw0, 128, 0, 0);
    gemm_kernel<512><<<N_NODES / 32, 256, 0, stream>>>(h, 512, g1W, nullptr, xw1, 128, 0, 0);

    // edge scatter-add
    gcn_scatter_kernel<<<NE / 8, 256, 0, stream>>>(s0, d0, deg0, xw0, agg0);
    gcn_scatter_kernel<<<NE / 8, 256, 0, stream>>>(s1, d1, deg1, xw1, agg1);

    // self term + bias + relu -> h2 [N,256]
    gcn_combine_kernel<<<N_NODES / 2, 256, 0, stream>>>(agg0, xw0, deg0, g0b, h2, 0);
    gcn_combine_kernel<<<N_NODES / 2, 256, 0, stream>>>(agg1, xw1, deg1, g1b, h2, 128);

    // z = relu(h2 @ c3W + c3b)   (K=256)
    gemm_kernel<256><<<N_NODES / 32, 256, 0, stream>>>(h2, 256, c3W, c3b, z, 128, 0, 1);

    // out = z_flat @ clsW + clsb
    classifier_kernel<<<2048, 256, 0, stream>>>(z, clsW, clsb, (float*)d_out);
}

// Round 2
// 2497.110 us; speedup vs baseline: 1.9994x; 1.9994x over previous
//
#include <hip/hip_runtime.h>
#include <hip/hip_bf16.h>

#define N_NODES 20000
#define NE      400000
#define HDIM    256

// ---------------------------------------------------------------------------
// CSR build: count -> scan (single block) -> scatter
// ---------------------------------------------------------------------------
__global__ void count_kernel(const int* __restrict__ dst0, int* cnt0,
                             const int* __restrict__ dst1, int* cnt1) {
    int e = blockIdx.x * blockDim.x + threadIdx.x;
    if (e < NE) {
        atomicAdd(&cnt0[dst0[e]], 1);
        atomicAdd(&cnt1[dst1[e]], 1);
    }
}

// exclusive scan of cnt[0..n) -> offs, cursor; offs[n]=total; dinv=rsqrt(1+cnt)
__global__ __launch_bounds__(256) void scan_kernel(
    const int* __restrict__ cnt, int* offs, int* cursor, float* dinv, int n)
{
    __shared__ int wsum[4];
    __shared__ int carry;
    int t = threadIdx.x, lane = t & 63, w = t >> 6;
    if (t == 0) carry = 0;
    __syncthreads();
    for (int base = 0; base < n; base += 256) {
        int i = base + t;
        int v = (i < n) ? cnt[i] : 0;
        int s = v;
        #pragma unroll
        for (int off = 1; off < 64; off <<= 1) {
            int x = __shfl_up(s, off);
            if (lane >= off) s += x;
        }
        if (lane == 63) wsum[w] = s;
        __syncthreads();
        int add = carry;
        for (int q = 0; q < w; ++q) add += wsum[q];
        if (i < n) {
            int excl = add + s - v;
            offs[i] = excl;
            cursor[i] = excl;
            dinv[i] = rsqrtf(1.0f + (float)v);
        }
        __syncthreads();
        if (t == 0) carry += wsum[0] + wsum[1] + wsum[2] + wsum[3];
        __syncthreads();
    }
    if (t == 0) offs[n] = carry;
}

__global__ void scatter_kernel(const int* __restrict__ dst0, int* cur0, int* eid0,
                               const int* __restrict__ dst1, int* cur1, int* eid1) {
    int e = blockIdx.x * blockDim.x + threadIdx.x;
    if (e < NE) {
        int p0 = atomicAdd(&cur0[dst0[e]], 1); eid0[p0] = e;
        int p1 = atomicAdd(&cur1[dst1[e]], 1); eid1[p1] = e;
    }
}

// ---------------------------------------------------------------------------
// PointNet, CSR-gather form. Block owns 4 consecutive nodes and ALL their
// edges; processes 32-edge chunks: hidden = relu(ef@W1+b1) into LDS,
// m = hidden@W2 in registers (4 edges x 8 ch per thread, conflict-free
// s_w2 reads), per-chunk segmented max into 4x256 LDS u32, final plain store.
// No global atomics; empty segments naturally produce 0 == relu(max) semantics.
// ---------------------------------------------------------------------------
__global__ __launch_bounds__(256) void pointnet_csr_kernel(
    const float* __restrict__ pos,
    const int* __restrict__ src, const int* __restrict__ dst,
    const int* __restrict__ eid, const int* __restrict__ offs,
    const float* __restrict__ W1, const float* __restrict__ b1,
    const float* __restrict__ W2, const float* __restrict__ b2,
    float* __restrict__ out, int co)
{
    __shared__ float s_ef[32][8];
    __shared__ int   s_lid[32];
    __shared__ float s_w1[6][256];
    __shared__ float s_b1[256];
    __shared__ float s_b2[256];
    __shared__ float s_hid[256][32];       // [k][edge]
    __shared__ float s_w2[16][256];        // K-chunk of W2
    __shared__ unsigned int sacc[4][256];  // per-node running max (>=0)

    const int t = threadIdx.x;
    const int nb = blockIdx.x * 4;

    #pragma unroll
    for (int j = 0; j < 6; ++j) s_w1[j][t] = W1[j * 256 + t];
    s_b1[t] = b1[t];
    s_b2[t] = b2[t];
    #pragma unroll
    for (int ln = 0; ln < 4; ++ln) sacc[ln][t] = 0u;

    const int estart = offs[nb];
    const int eend   = offs[nb + 4];
    __syncthreads();

    const int cg = t & 31;  const int ca = cg * 4;  const int cb = 128 + cg * 4;
    const int eg = t >> 5;  const int e0 = eg * 4;

    for (int ebase = estart; ebase < eend; ebase += 32) {
        // ---- edge metadata ----
        if (t < 32) {
            int slot = ebase + t;
            int lid = -1;
            float f0 = 0.f, f1 = 0.f, f2 = 0.f, f3 = 0.f, f4 = 0.f, f5 = 0.f;
            if (slot < eend) {
                int e = eid[slot];
                int s = src[e], d = dst[e];
                lid = d - nb;
                float sx = pos[s * 3 + 0], sy = pos[s * 3 + 1], sz = pos[s * 3 + 2];
                float dx = pos[d * 3 + 0], dy = pos[d * 3 + 1], dz = pos[d * 3 + 2];
                f0 = sx; f1 = sy; f2 = sz;
                f3 = sx - dx; f4 = sy - dy; f5 = sz - dz;
            }
            s_lid[t] = lid;
            s_ef[t][0] = f0; s_ef[t][1] = f1; s_ef[t][2] = f2;
            s_ef[t][3] = f3; s_ef[t][4] = f4; s_ef[t][5] = f5;
        }
        __syncthreads();

        // ---- phase 1: hidden ----
        {
            int e  = t & 31;
            int k0 = (t >> 5) * 32;
            float f0 = s_ef[e][0], f1 = s_ef[e][1], f2 = s_ef[e][2];
            float f3 = s_ef[e][3], f4 = s_ef[e][4], f5 = s_ef[e][5];
            #pragma unroll 8
            for (int kk = 0; kk < 32; ++kk) {
                int k = k0 + kk;
                float h = s_b1[k];
                h += f0 * s_w1[0][k]; h += f1 * s_w1[1][k]; h += f2 * s_w1[2][k];
                h += f3 * s_w1[3][k]; h += f4 * s_w1[4][k]; h += f5 * s_w1[5][k];
                s_hid[k][e] = fmaxf(h, 0.f);
            }
        }
        __syncthreads();

        // ---- phase 2: m = hidden @ W2 ----
        float acc[4][8];
        #pragma unroll
        for (int i = 0; i < 4; ++i)
            #pragma unroll
            for (int j = 0; j < 8; ++j) acc[i][j] = 0.f;

        for (int kc = 0; kc < 256; kc += 16) {
            // stage 16x256 of W2: 4096 floats = 1024 float4, 4 per thread
            #pragma unroll
            for (int it = 0; it < 4; ++it) {
                int f  = it * 256 + t;
                int r  = f >> 6;
                int c4 = (f & 63) * 4;
                *(float4*)&s_w2[r][c4] = *(const float4*)&W2[(kc + r) * 256 + c4];
            }
            __syncthreads();
            #pragma unroll 4
            for (int kk = 0; kk < 16; ++kk) {
                float4 hv = *(const float4*)&s_hid[kc + kk][e0];
                float4 wa = *(const float4*)&s_w2[kk][ca];
                float4 wb = *(const float4*)&s_w2[kk][cb];
                float h_[4] = {hv.x, hv.y, hv.z, hv.w};
                float wA[4] = {wa.x, wa.y, wa.z, wa.w};
                float wB[4] = {wb.x, wb.y, wb.z, wb.w};
                #pragma unroll
                for (int i = 0; i < 4; ++i) {
                    #pragma unroll
                    for (int j = 0; j < 4; ++j) acc[i][j]     += h_[i] * wA[j];
                    #pragma unroll
                    for (int j = 0; j < 4; ++j) acc[i][4 + j] += h_[i] * wB[j];
                }
            }
            __syncthreads();
        }

        // ---- chunk epilogue: segmented max into LDS ----
        #pragma unroll
        for (int i = 0; i < 4; ++i) {
            int lid = s_lid[e0 + i];
            if (lid >= 0) {
                #pragma unroll
                for (int j = 0; j < 4; ++j) {
                    float m = acc[i][j] + s_b2[ca + j];
                    if (m > 0.f) atomicMax(&sacc[lid][ca + j], __float_as_uint(m));
                }
                #pragma unroll
                for (int j = 0; j < 4; ++j) {
                    float m = acc[i][4 + j] + s_b2[cb + j];
                    if (m > 0.f) atomicMax(&sacc[lid][cb + j], __float_as_uint(m));
                }
            }
        }
        __syncthreads();
    }

    // ---- final store: plain, coalesced; covers every owned node ----
    #pragma unroll
    for (int ln = 0; ln < 4; ++ln)
        out[(size_t)(nb + ln) * 512 + co + t] = __uint_as_float(sacc[ln][t]);
}

// ---------------------------------------------------------------------------
// Generic fp32 GEMM: C[:, cco:cco+128] = opt_relu(A[M,K] @ W[K,128] + bias)
// block 256, tile 32 rows x 128 cols, grid = M/32. K % 64 == 0.
// ---------------------------------------------------------------------------
template <int KDIM>
__global__ __launch_bounds__(256) void gemm_kernel(
    const float* __restrict__ A, int lda,
    const float* __restrict__ W,
    const float* __restrict__ bias,
    float* __restrict__ C, int ldc, int cco, int dorelu)
{
    __shared__ float s_a[32][68];
    __shared__ float s_w[64][128];

    const int t  = threadIdx.x;
    const int mb = blockIdx.x * 32;
    const int tn = t & 31;  const int c0 = tn * 4;
    const int tm = t >> 5;  const int m0 = tm * 4;

    float acc[4][4];
    #pragma unroll
    for (int i = 0; i < 4; ++i)
        #pragma unroll
        for (int j = 0; j < 4; ++j) acc[i][j] = 0.f;

    for (int kc = 0; kc < KDIM; kc += 64) {
        __syncthreads();
        #pragma unroll
        for (int it = 0; it < 2; ++it) {
            int f  = it * 256 + t;
            int r  = f >> 4;
            int k4 = (f & 15) * 4;
            *(float4*)&s_a[r][k4] = *(const float4*)&A[(size_t)(mb + r) * lda + kc + k4];
        }
        #pragma unroll
        for (int it = 0; it < 8; ++it) {
            int f  = it * 256 + t;
            int r  = f >> 5;
            int c4 = (f & 31) * 4;
            *(float4*)&s_w[r][c4] = *(const float4*)&W[(size_t)(kc + r) * 128 + c4];
        }
        __syncthreads();
        #pragma unroll 8
        for (int kk = 0; kk < 64; ++kk) {
            float4 wv = *(const float4*)&s_w[kk][c0];
            float av[4];
            #pragma unroll
            for (int i = 0; i < 4; ++i) av[i] = s_a[m0 + i][kk];
            #pragma unroll
            for (int i = 0; i < 4; ++i) {
                acc[i][0] += av[i] * wv.x;
                acc[i][1] += av[i] * wv.y;
                acc[i][2] += av[i] * wv.z;
                acc[i][3] += av[i] * wv.w;
            }
        }
    }

    #pragma unroll
    for (int i = 0; i < 4; ++i) {
        int row = mb + m0 + i;
        float4 v;
        v.x = acc[i][0]; v.y = acc[i][1]; v.z = acc[i][2]; v.w = acc[i][3];
        if (bias) { v.x += bias[c0]; v.y += bias[c0 + 1]; v.z += bias[c0 + 2]; v.w += bias[c0 + 3]; }
        if (dorelu) { v.x = fmaxf(v.x, 0.f); v.y = fmaxf(v.y, 0.f); v.z = fmaxf(v.z, 0.f); v.w = fmaxf(v.w, 0.f); }
        *(float4*)&C[(size_t)row * ldc + cco + c0] = v;
    }
}

// ---------------------------------------------------------------------------
// Fused GCN: gather-based aggregation (no atomics) + self term + bias + relu.
// One 128-thread block per node; thread t = channel t.
// h2[i][co+c] = relu( sum_e xw[src_e][c]*dinv[src_e]*dinv[i]
//                     + xw[i][c]*dinv[i]^2 + b[c] )
// ---------------------------------------------------------------------------
__global__ __launch_bounds__(128) void gcn_gather_kernel(
    const int* __restrict__ src, const int* __restrict__ eid,
    const int* __restrict__ offs, const float* __restrict__ dinv,
    const float* __restrict__ xw, const float* __restrict__ b,
    float* __restrict__ h2, int co)
{
    __shared__ int   s_src[64];
    __shared__ float s_nrm[64];

    const int i = blockIdx.x;
    const int t = threadIdx.x;
    const int e0 = offs[i], e1 = offs[i + 1];
    const float di = dinv[i];

    float acc = 0.f;
    for (int base = e0; base < e1; base += 64) {
        int k = base + t;
        if (t < 64 && k < e1) {
            int e = eid[k];
            int s = src[e];
            s_src[t] = s;
            s_nrm[t] = dinv[s];
        }
        __syncthreads();
        int m = min(64, e1 - base);
        #pragma unroll 2
        for (int j = 0; j < m; ++j)
            acc += xw[(size_t)s_src[j] * 128 + t] * s_nrm[j];
        __syncthreads();
    }

    float xi = xw[(size_t)i * 128 + t];
    float v = acc * di + xi * di * di + b[t];
    h2[(size_t)i * 256 + co + t] = fmaxf(v, 0.f);
}

// ---------------------------------------------------------------------------
// Final classifier: out[3] = z_flat @ cls_W + cls_b  (out pre-zeroed)
// ---------------------------------------------------------------------------
__global__ __launch_bounds__(256) void classifier_kernel(
    const float* __restrict__ z, const float* __restrict__ clsW,
    const float* __restrict__ clsb, float* __restrict__ out)
{
    float a0 = 0.f, a1 = 0.f, a2 = 0.f;
    const int total = N_NODES * 128;
    for (int i = blockIdx.x * blockDim.x + threadIdx.x; i < total;
         i += gridDim.x * blockDim.x) {
        float v = z[i];
        a0 += v * clsW[(size_t)i * 3 + 0];
        a1 += v * clsW[(size_t)i * 3 + 1];
        a2 += v * clsW[(size_t)i * 3 + 2];
    }
    #pragma unroll
    for (int off = 32; off > 0; off >>= 1) {
        a0 += __shfl_down(a0, off);
        a1 += __shfl_down(a1, off);
        a2 += __shfl_down(a2, off);
    }
    __shared__ float sred[12];
    int w = threadIdx.x >> 6;
    if ((threadIdx.x & 63) == 0) { sred[w * 3] = a0; sred[w * 3 + 1] = a1; sred[w * 3 + 2] = a2; }
    __syncthreads();
    if (threadIdx.x == 0) {
        float r0 = 0.f, r1 = 0.f, r2 = 0.f;
        #pragma unroll
        for (int q = 0; q < 4; ++q) { r0 += sred[q * 3]; r1 += sred[q * 3 + 1]; r2 += sred[q * 3 + 2]; }
        atomicAdd(&out[0], r0); atomicAdd(&out[1], r1); atomicAdd(&out[2], r2);
    }
    if (blockIdx.x == 0 && threadIdx.x < 3) atomicAdd(&out[threadIdx.x], clsb[threadIdx.x]);
}

// ---------------------------------------------------------------------------
extern "C" void kernel_launch(void* const* d_in, const int* in_sizes, int n_in,
                              void* d_out, int out_size, void* d_ws, size_t ws_size,
                              hipStream_t stream) {
    const float* pos0 = (const float*)d_in[0];
    const float* pos1 = (const float*)d_in[1];
    const int*   ei0  = (const int*)d_in[2];
    const int*   ei1  = (const int*)d_in[3];
    const float* p0W1 = (const float*)d_in[6];
    const float* p0b1 = (const float*)d_in[7];
    const float* p0W2 = (const float*)d_in[8];
    const float* p0b2 = (const float*)d_in[9];
    const float* p1W1 = (const float*)d_in[10];
    const float* p1b1 = (const float*)d_in[11];
    const float* p1W2 = (const float*)d_in[12];
    const float* p1b2 = (const float*)d_in[13];
    const float* g0W  = (const float*)d_in[14];
    const float* g0b  = (const float*)d_in[15];
    const float* g1W  = (const float*)d_in[16];
    const float* g1b  = (const float*)d_in[17];
    const float* c3W  = (const float*)d_in[18];
    const float* c3b  = (const float*)d_in[19];
    const float* clsW = (const float*)d_in[20];
    const float* clsb = (const float*)d_in[21];

    const int* s0 = ei0;       const int* d0 = ei0 + NE;
    const int* s1 = ei1;       const int* d1 = ei1 + NE;

    float* ws = (float*)d_ws;
    float* h     = ws;                       // [N,512]   10,240,000 f
    float* xw0   = ws + 10240000;            // [N,128]
    float* xw1   = ws + 12800000;            // [N,128]
    float* h2    = ws + 15360000;            // [N,256]
    float* z     = ws + 20480000;            // [N,128]
    int*   cnt0  = (int*)(ws + 23040000);    // [N]
    int*   cnt1  = (int*)(ws + 23060000);
    int*   cur0  = (int*)(ws + 23080000);
    int*   cur1  = (int*)(ws + 23100000);
    int*   offs0 = (int*)(ws + 23120000);    // [N+1]
    int*   offs1 = (int*)(ws + 23140004);    // [N+1]
    int*   eid0  = (int*)(ws + 23160008);    // [E]
    int*   eid1  = (int*)(ws + 23560008);
    float* dinv0 = ws + 23960008;            // [N]
    float* dinv1 = ws + 23980008;

    // zero: counts (contiguous 160 KB) + out
    hipMemsetAsync(cnt0, 0, (size_t)2 * N_NODES * sizeof(int), stream);
    hipMemsetAsync(d_out, 0, 3 * sizeof(float), stream);

    // CSR build (by dst) for both edge sets
    count_kernel<<<(NE + 255) / 256, 256, 0, stream>>>(d0, cnt0, d1, cnt1);
    scan_kernel<<<1, 256, 0, stream>>>(cnt0, offs0, cur0, dinv0, N_NODES);
    scan_kernel<<<1, 256, 0, stream>>>(cnt1, offs1, cur1, dinv1, N_NODES);
    scatter_kernel<<<(NE + 255) / 256, 256, 0, stream>>>(d0, cur0, eid0, d1, cur1, eid1);

    // PointNet layers -> h[N, 0:256], h[N, 256:512]  (no global atomics)
    pointnet_csr_kernel<<<N_NODES / 4, 256, 0, stream>>>(
        pos0, s0, d0, eid0, offs0, p0W1, p0b1, p0W2, p0b2, h, 0);
    pointnet_csr_kernel<<<N_NODES / 4, 256, 0, stream>>>(
        pos1, s1, d1, eid1, offs1, p1W1, p1b1, p1W2, p1b2, h, 256);

    // xw = h @ gW   (K=512)
    gemm_kernel<512><<<N_NODES / 32, 256, 0, stream>>>(h, 512, g0W, nullptr, xw0, 128, 0, 0);
    gemm_kernel<512><<<N_NODES / 32, 256, 0, stream>>>(h, 512, g1W, nullptr, xw1, 128, 0, 0);

    // fused GCN aggregation (gather) + self term + bias + relu -> h2 [N,256]
    gcn_gather_kernel<<<N_NODES, 128, 0, stream>>>(s0, eid0, offs0, dinv0, xw0, g0b, h2, 0);
    gcn_gather_kernel<<<N_NODES, 128, 0, stream>>>(s1, eid1, offs1, dinv1, xw1, g1b, h2, 128);

    // z = relu(h2 @ c3W + c3b)   (K=256)
    gemm_kernel<256><<<N_NODES / 32, 256, 0, stream>>>(h2, 256, c3W, c3b, z, 128, 0, 1);

    // out = z_flat @ clsW + clsb
    classifier_kernel<<<2048, 256, 0, stream>>>(z, clsW, clsb, (float*)d_out);
}

// Round 3
// 904.917 us; speedup vs baseline: 5.5174x; 2.7595x over previous
//
#include <hip/hip_runtime.h>
#include <hip/hip_bf16.h>

#define N_NODES 20000
#define NE      400000
#define HDIM    256

typedef _Float16 half8 __attribute__((ext_vector_type(8)));
typedef float    floatx4 __attribute__((ext_vector_type(4)));

// ---------------------------------------------------------------------------
// CSR build: count -> scan (single block) -> scatter
// ---------------------------------------------------------------------------
__global__ void count_kernel(const int* __restrict__ dst0, int* cnt0,
                             const int* __restrict__ dst1, int* cnt1) {
    int e = blockIdx.x * blockDim.x + threadIdx.x;
    if (e < NE) {
        atomicAdd(&cnt0[dst0[e]], 1);
        atomicAdd(&cnt1[dst1[e]], 1);
    }
}

__global__ __launch_bounds__(256) void scan_kernel(
    const int* __restrict__ cnt, int* offs, int* cursor, float* dinv, int n)
{
    __shared__ int wsum[4];
    __shared__ int carry;
    int t = threadIdx.x, lane = t & 63, w = t >> 6;
    if (t == 0) carry = 0;
    __syncthreads();
    for (int base = 0; base < n; base += 256) {
        int i = base + t;
        int v = (i < n) ? cnt[i] : 0;
        int s = v;
        #pragma unroll
        for (int off = 1; off < 64; off <<= 1) {
            int x = __shfl_up(s, off);
            if (lane >= off) s += x;
        }
        if (lane == 63) wsum[w] = s;
        __syncthreads();
        int add = carry;
        for (int q = 0; q < w; ++q) add += wsum[q];
        if (i < n) {
            int excl = add + s - v;
            offs[i] = excl;
            cursor[i] = excl;
            dinv[i] = rsqrtf(1.0f + (float)v);
        }
        __syncthreads();
        if (t == 0) carry += wsum[0] + wsum[1] + wsum[2] + wsum[3];
        __syncthreads();
    }
    if (t == 0) offs[n] = carry;
}

__global__ void scatter_kernel(const int* __restrict__ dst0, int* cur0, int* eid0,
                               const int* __restrict__ dst1, int* cur1, int* eid1) {
    int e = blockIdx.x * blockDim.x + threadIdx.x;
    if (e < NE) {
        int p0 = atomicAdd(&cur0[dst0[e]], 1); eid0[p0] = e;
        int p1 = atomicAdd(&cur1[dst1[e]], 1); eid1[p1] = e;
    }
}

// ---------------------------------------------------------------------------
// W2 -> fragment-ordered fp16 B-operands for mfma_f32_16x16x32_f16.
// Bf[((nt*8+ks)*64 + lane)*8 + j] = W2[ks*32 + (lane>>4)*8 + j][nt*16 + (lane&15)]
// 16 Ntiles x 8 Ksteps x 64 lanes x 8 halfs = 128 KB.
// ---------------------------------------------------------------------------
__global__ __launch_bounds__(256) void w2frag_kernel(
    const float* __restrict__ W2, _Float16* __restrict__ Bf)
{
    int tid = blockIdx.x * 256 + threadIdx.x;   // 0..8191
    int l  = tid & 63;
    int ks = (tid >> 6) & 7;
    int nt = tid >> 9;
    int n  = nt * 16 + (l & 15);
    int kb = ks * 32 + (l >> 4) * 8;
    half8 v;
    #pragma unroll
    for (int j = 0; j < 8; ++j) v[j] = (_Float16)W2[(kb + j) * 256 + n];
    *(half8*)&Bf[(size_t)tid * 8] = v;
}

// ---------------------------------------------------------------------------
// PointNet, CSR + MFMA. Block = 256 thr (4 waves), owns 4 nodes, 32-edge chunks.
// Phase 1 (fp32 VALU): hidden = relu(ef@W1+b1), written as fp16 A-frags to LDS.
// Phase 2 (MFMA f16): m = hidden @ W2; wave w covers channels [w*64, w*64+64),
// both M-tiles; B-frags loaded global->reg (L1/L2-resident).
// Epilogue: LDS u32 atomicMax segmented max; final plain coalesced store.
// ---------------------------------------------------------------------------
__global__ __launch_bounds__(256) void pointnet_mfma_kernel(
    const float* __restrict__ pos,
    const int* __restrict__ src, const int* __restrict__ dst,
    const int* __restrict__ eid, const int* __restrict__ offs,
    const float* __restrict__ W1, const float* __restrict__ b1,
    const _Float16* __restrict__ Bf, const float* __restrict__ b2,
    float* __restrict__ out, int co)
{
    __shared__ float s_ef[32][8];
    __shared__ int   s_lid[32];
    __shared__ float s_w1[6][256];
    __shared__ float s_b1[256];
    __shared__ float s_b2[256];
    __shared__ _Float16 s_afr[2 * 8 * 64 * 8];   // [mt][ks][lane][8] = 16 KB
    __shared__ unsigned int sacc[4][256];

    const int t = threadIdx.x;
    const int nb = blockIdx.x * 4;

    #pragma unroll
    for (int j = 0; j < 6; ++j) s_w1[j][t] = W1[j * 256 + t];
    s_b1[t] = b1[t];
    s_b2[t] = b2[t];
    #pragma unroll
    for (int ln = 0; ln < 4; ++ln) sacc[ln][t] = 0u;

    const int estart = offs[nb];
    const int eend   = offs[nb + 4];
    __syncthreads();

    const int lane = t & 63;
    const int wv   = t >> 6;
    const int e    = t & 31;     // phase-1 edge
    const int ksid = t >> 5;     // phase-1 K-step (0..7)

    for (int ebase = estart; ebase < eend; ebase += 32) {
        // ---- edge metadata ----
        if (t < 32) {
            int slot = ebase + t;
            int lid = -1;
            float f0 = 0.f, f1 = 0.f, f2 = 0.f, f3 = 0.f, f4 = 0.f, f5 = 0.f;
            if (slot < eend) {
                int ed = eid[slot];
                int s = src[ed], d = dst[ed];
                lid = d - nb;
                float sx = pos[s * 3 + 0], sy = pos[s * 3 + 1], sz = pos[s * 3 + 2];
                float dx = pos[d * 3 + 0], dy = pos[d * 3 + 1], dz = pos[d * 3 + 2];
                f0 = sx; f1 = sy; f2 = sz;
                f3 = sx - dx; f4 = sy - dy; f5 = sz - dz;
            }
            s_lid[t] = lid;
            s_ef[t][0] = f0; s_ef[t][1] = f1; s_ef[t][2] = f2;
            s_ef[t][3] = f3; s_ef[t][4] = f4; s_ef[t][5] = f5;
        }
        __syncthreads();

        // ---- phase 1: hidden -> fp16 A-frags ----
        {
            float f0 = s_ef[e][0], f1 = s_ef[e][1], f2 = s_ef[e][2];
            float f3 = s_ef[e][3], f4 = s_ef[e][4], f5 = s_ef[e][5];
            int mt = e >> 4, m = e & 15;
            #pragma unroll
            for (int q = 0; q < 4; ++q) {
                half8 hv;
                #pragma unroll
                for (int j = 0; j < 8; ++j) {
                    int k = ksid * 32 + q * 8 + j;
                    float h = s_b1[k];
                    h += f0 * s_w1[0][k]; h += f1 * s_w1[1][k]; h += f2 * s_w1[2][k];
                    h += f3 * s_w1[3][k]; h += f4 * s_w1[4][k]; h += f5 * s_w1[5][k];
                    hv[j] = (_Float16)fmaxf(h, 0.f);
                }
                int fl = (mt * 8 + ksid) * 64 + m + 16 * q;
                *(half8*)&s_afr[fl * 8] = hv;
            }
        }
        __syncthreads();

        // ---- phase 2: MFMA ----
        floatx4 acc[2][4];
        #pragma unroll
        for (int mt = 0; mt < 2; ++mt)
            #pragma unroll
            for (int q = 0; q < 4; ++q) acc[mt][q] = (floatx4){0.f, 0.f, 0.f, 0.f};

        #pragma unroll
        for (int ks = 0; ks < 8; ++ks) {
            half8 a0 = *(const half8*)&s_afr[((0 * 8 + ks) * 64 + lane) * 8];
            half8 a1 = *(const half8*)&s_afr[((1 * 8 + ks) * 64 + lane) * 8];
            #pragma unroll
            for (int q = 0; q < 4; ++q) {
                int nt = wv * 4 + q;
                half8 b = *(const half8*)&Bf[(size_t)((nt * 8 + ks) * 64 + lane) * 8];
                acc[0][q] = __builtin_amdgcn_mfma_f32_16x16x32_f16(a0, b, acc[0][q], 0, 0, 0);
                acc[1][q] = __builtin_amdgcn_mfma_f32_16x16x32_f16(a1, b, acc[1][q], 0, 0, 0);
            }
        }

        // ---- epilogue: segmented max into LDS ----
        {
            int rbase = (lane >> 4) * 4;
            #pragma unroll
            for (int q = 0; q < 4; ++q) {
                int ch = (wv * 4 + q) * 16 + (lane & 15);
                float bb = s_b2[ch];
                #pragma unroll
                for (int mt = 0; mt < 2; ++mt) {
                    #pragma unroll
                    for (int r = 0; r < 4; ++r) {
                        int lid = s_lid[mt * 16 + rbase + r];
                        float m = acc[mt][q][r] + bb;
                        if (lid >= 0 && m > 0.f)
                            atomicMax(&sacc[lid][ch], __float_as_uint(m));
                    }
                }
            }
        }
        __syncthreads();
    }

    // ---- final store ----
    #pragma unroll
    for (int ln = 0; ln < 4; ++ln)
        out[(size_t)(nb + ln) * 512 + co + t] = __uint_as_float(sacc[ln][t]);
}

// ---------------------------------------------------------------------------
// Generic fp32 GEMM: C[:, cco:cco+128] = opt_relu(A[M,K] @ W[K,128] + bias)
// ---------------------------------------------------------------------------
template <int KDIM>
__global__ __launch_bounds__(256) void gemm_kernel(
    const float* __restrict__ A, int lda,
    const float* __restrict__ W,
    const float* __restrict__ bias,
    float* __restrict__ C, int ldc, int cco, int dorelu)
{
    __shared__ float s_a[32][68];
    __shared__ float s_w[64][128];

    const int t  = threadIdx.x;
    const int mb = blockIdx.x * 32;
    const int tn = t & 31;  const int c0 = tn * 4;
    const int tm = t >> 5;  const int m0 = tm * 4;

    float acc[4][4];
    #pragma unroll
    for (int i = 0; i < 4; ++i)
        #pragma unroll
        for (int j = 0; j < 4; ++j) acc[i][j] = 0.f;

    for (int kc = 0; kc < KDIM; kc += 64) {
        __syncthreads();
        #pragma unroll
        for (int it = 0; it < 2; ++it) {
            int f  = it * 256 + t;
            int r  = f >> 4;
            int k4 = (f & 15) * 4;
            *(float4*)&s_a[r][k4] = *(const float4*)&A[(size_t)(mb + r) * lda + kc + k4];
        }
        #pragma unroll
        for (int it = 0; it < 8; ++it) {
            int f  = it * 256 + t;
            int r  = f >> 5;
            int c4 = (f & 31) * 4;
            *(float4*)&s_w[r][c4] = *(const float4*)&W[(size_t)(kc + r) * 128 + c4];
        }
        __syncthreads();
        #pragma unroll 8
        for (int kk = 0; kk < 64; ++kk) {
            float4 wv = *(const float4*)&s_w[kk][c0];
            float av[4];
            #pragma unroll
            for (int i = 0; i < 4; ++i) av[i] = s_a[m0 + i][kk];
            #pragma unroll
            for (int i = 0; i < 4; ++i) {
                acc[i][0] += av[i] * wv.x;
                acc[i][1] += av[i] * wv.y;
                acc[i][2] += av[i] * wv.z;
                acc[i][3] += av[i] * wv.w;
            }
        }
    }

    #pragma unroll
    for (int i = 0; i < 4; ++i) {
        int row = mb + m0 + i;
        float4 v;
        v.x = acc[i][0]; v.y = acc[i][1]; v.z = acc[i][2]; v.w = acc[i][3];
        if (bias) { v.x += bias[c0]; v.y += bias[c0 + 1]; v.z += bias[c0 + 2]; v.w += bias[c0 + 3]; }
        if (dorelu) { v.x = fmaxf(v.x, 0.f); v.y = fmaxf(v.y, 0.f); v.z = fmaxf(v.z, 0.f); v.w = fmaxf(v.w, 0.f); }
        *(float4*)&C[(size_t)row * ldc + cco + c0] = v;
    }
}

// ---------------------------------------------------------------------------
// Fused GCN gather: no atomics.
// ---------------------------------------------------------------------------
__global__ __launch_bounds__(128) void gcn_gather_kernel(
    const int* __restrict__ src, const int* __restrict__ eid,
    const int* __restrict__ offs, const float* __restrict__ dinv,
    const float* __restrict__ xw, const float* __restrict__ b,
    float* __restrict__ h2, int co)
{
    __shared__ int   s_src[64];
    __shared__ float s_nrm[64];

    const int i = blockIdx.x;
    const int t = threadIdx.x;
    const int e0 = offs[i], e1 = offs[i + 1];
    const float di = dinv[i];

    float acc = 0.f;
    for (int base = e0; base < e1; base += 64) {
        int k = base + t;
        if (t < 64 && k < e1) {
            int e = eid[k];
            int s = src[e];
            s_src[t] = s;
            s_nrm[t] = dinv[s];
        }
        __syncthreads();
        int m = min(64, e1 - base);
        #pragma unroll 2
        for (int j = 0; j < m; ++j)
            acc += xw[(size_t)s_src[j] * 128 + t] * s_nrm[j];
        __syncthreads();
    }

    float xi = xw[(size_t)i * 128 + t];
    float v = acc * di + xi * di * di + b[t];
    h2[(size_t)i * 256 + co + t] = fmaxf(v, 0.f);
}

// ---------------------------------------------------------------------------
// Final classifier: out[3] = z_flat @ cls_W + cls_b  (out pre-zeroed)
// ---------------------------------------------------------------------------
__global__ __launch_bounds__(256) void classifier_kernel(
    const float* __restrict__ z, const float* __restrict__ clsW,
    const float* __restrict__ clsb, float* __restrict__ out)
{
    float a0 = 0.f, a1 = 0.f, a2 = 0.f;
    const int total = N_NODES * 128;
    for (int i = blockIdx.x * blockDim.x + threadIdx.x; i < total;
         i += gridDim.x * blockDim.x) {
        float v = z[i];
        a0 += v * clsW[(size_t)i * 3 + 0];
        a1 += v * clsW[(size_t)i * 3 + 1];
        a2 += v * clsW[(size_t)i * 3 + 2];
    }
    #pragma unroll
    for (int off = 32; off > 0; off >>= 1) {
        a0 += __shfl_down(a0, off);
        a1 += __shfl_down(a1, off);
        a2 += __shfl_down(a2, off);
    }
    __shared__ float sred[12];
    int w = threadIdx.x >> 6;
    if ((threadIdx.x & 63) == 0) { sred[w * 3] = a0; sred[w * 3 + 1] = a1; sred[w * 3 + 2] = a2; }
    __syncthreads();
    if (threadIdx.x == 0) {
        float r0 = 0.f, r1 = 0.f, r2 = 0.f;
        #pragma unroll
        for (int q = 0; q < 4; ++q) { r0 += sred[q * 3]; r1 += sred[q * 3 + 1]; r2 += sred[q * 3 + 2]; }
        atomicAdd(&out[0], r0); atomicAdd(&out[1], r1); atomicAdd(&out[2], r2);
    }
    if (blockIdx.x == 0 && threadIdx.x < 3) atomicAdd(&out[threadIdx.x], clsb[threadIdx.x]);
}

// ---------------------------------------------------------------------------
extern "C" void kernel_launch(void* const* d_in, const int* in_sizes, int n_in,
                              void* d_out, int out_size, void* d_ws, size_t ws_size,
                              hipStream_t stream) {
    const float* pos0 = (const float*)d_in[0];
    const float* pos1 = (const float*)d_in[1];
    const int*   ei0  = (const int*)d_in[2];
    const int*   ei1  = (const int*)d_in[3];
    const float* p0W1 = (const float*)d_in[6];
    const float* p0b1 = (const float*)d_in[7];
    const float* p0W2 = (const float*)d_in[8];
    const float* p0b2 = (const float*)d_in[9];
    const float* p1W1 = (const float*)d_in[10];
    const float* p1b1 = (const float*)d_in[11];
    const float* p1W2 = (const float*)d_in[12];
    const float* p1b2 = (const float*)d_in[13];
    const float* g0W  = (const float*)d_in[14];
    const float* g0b  = (const float*)d_in[15];
    const float* g1W  = (const float*)d_in[16];
    const float* g1b  = (const float*)d_in[17];
    const float* c3W  = (const float*)d_in[18];
    const float* c3b  = (const float*)d_in[19];
    const float* clsW = (const float*)d_in[20];
    const float* clsb = (const float*)d_in[21];

    const int* s0 = ei0;       const int* d0 = ei0 + NE;
    const int* s1 = ei1;       const int* d1 = ei1 + NE;

    float* ws = (float*)d_ws;
    float* h     = ws;                       // [N,512]
    float* xw0   = ws + 10240000;            // [N,128]
    float* xw1   = ws + 12800000;            // [N,128]
    float* h2    = ws + 15360000;            // [N,256]
    float* z     = ws + 20480000;            // [N,128]
    int*   cnt0  = (int*)(ws + 23040000);    // [N]
    int*   cnt1  = (int*)(ws + 23060000);
    int*   cur0  = (int*)(ws + 23080000);
    int*   cur1  = (int*)(ws + 23100000);
    int*   offs0 = (int*)(ws + 23120000);    // [N+1]
    int*   offs1 = (int*)(ws + 23140004);    // [N+1]
    int*   eid0  = (int*)(ws + 23160008);    // [E]
    int*   eid1  = (int*)(ws + 23560008);
    float* dinv0 = ws + 23960008;            // [N]
    float* dinv1 = ws + 23980008;
    _Float16* w2f0 = (_Float16*)(ws + 24000008);  // 65536 halfs (16B-aligned)
    _Float16* w2f1 = (_Float16*)(ws + 24032776);

    hipMemsetAsync(cnt0, 0, (size_t)2 * N_NODES * sizeof(int), stream);
    hipMemsetAsync(d_out, 0, 3 * sizeof(float), stream);

    // CSR build (by dst) + W2 fragment conversion
    count_kernel<<<(NE + 255) / 256, 256, 0, stream>>>(d0, cnt0, d1, cnt1);
    w2frag_kernel<<<32, 256, 0, stream>>>(p0W2, w2f0);
    w2frag_kernel<<<32, 256, 0, stream>>>(p1W2, w2f1);
    scan_kernel<<<1, 256, 0, stream>>>(cnt0, offs0, cur0, dinv0, N_NODES);
    scan_kernel<<<1, 256, 0, stream>>>(cnt1, offs1, cur1, dinv1, N_NODES);
    scatter_kernel<<<(NE + 255) / 256, 256, 0, stream>>>(d0, cur0, eid0, d1, cur1, eid1);

    // PointNet layers -> h[N, 0:256], h[N, 256:512]
    pointnet_mfma_kernel<<<N_NODES / 4, 256, 0, stream>>>(
        pos0, s0, d0, eid0, offs0, p0W1, p0b1, w2f0, p0b2, h, 0);
    pointnet_mfma_kernel<<<N_NODES / 4, 256, 0, stream>>>(
        pos1, s1, d1, eid1, offs1, p1W1, p1b1, w2f1, p1b2, h, 256);

    // xw = h @ gW   (K=512)
    gemm_kernel<512><<<N_NODES / 32, 256, 0, stream>>>(h, 512, g0W, nullptr, xw0, 128, 0, 0);
    gemm_kernel<512><<<N_NODES / 32, 256, 0, stream>>>(h, 512, g1W, nullptr, xw1, 128, 0, 0);

    // fused GCN aggregation (gather) -> h2 [N,256]
    gcn_gather_kernel<<<N_NODES, 128, 0, stream>>>(s0, eid0, offs0, dinv0, xw0, g0b, h2, 0);
    gcn_gather_kernel<<<N_NODES, 128, 0, stream>>>(s1, eid1, offs1, dinv1, xw1, g1b, h2, 128);

    // z = relu(h2 @ c3W + c3b)   (K=256)
    gemm_kernel<256><<<N_NODES / 32, 256, 0, stream>>>(h2, 256, c3W, c3b, z, 128, 0, 1);

    // out = z_flat @ clsW + clsb
    classifier_kernel<<<2048, 256, 0, stream>>>(z, clsW, clsb, (float*)d_out);
}

// Round 4
// 815.026 us; speedup vs baseline: 6.1260x; 1.1103x over previous
//
#include <hip/hip_runtime.h>
#include <hip/hip_bf16.h>

#define N_NODES 20000
#define NE      400000
#define HDIM    256

typedef _Float16 half8 __attribute__((ext_vector_type(8)));
typedef _Float16 half2v __attribute__((ext_vector_type(2)));
typedef float    floatx4 __attribute__((ext_vector_type(4)));

// ---------------------------------------------------------------------------
// CSR build: count -> scan (single block) -> scatter
// ---------------------------------------------------------------------------
__global__ void count_kernel(const int* __restrict__ dst0, int* cnt0,
                             const int* __restrict__ dst1, int* cnt1) {
    int e = blockIdx.x * blockDim.x + threadIdx.x;
    if (e < NE) {
        atomicAdd(&cnt0[dst0[e]], 1);
        atomicAdd(&cnt1[dst1[e]], 1);
    }
}

__global__ __launch_bounds__(256) void scan_kernel(
    const int* __restrict__ cnt, int* offs, int* cursor, float* dinv, int n)
{
    __shared__ int wsum[4];
    __shared__ int carry;
    int t = threadIdx.x, lane = t & 63, w = t >> 6;
    if (t == 0) carry = 0;
    __syncthreads();
    for (int base = 0; base < n; base += 256) {
        int i = base + t;
        int v = (i < n) ? cnt[i] : 0;
        int s = v;
        #pragma unroll
        for (int off = 1; off < 64; off <<= 1) {
            int x = __shfl_up(s, off);
            if (lane >= off) s += x;
        }
        if (lane == 63) wsum[w] = s;
        __syncthreads();
        int add = carry;
        for (int q = 0; q < w; ++q) add += wsum[q];
        if (i < n) {
            int excl = add + s - v;
            offs[i] = excl;
            cursor[i] = excl;
            dinv[i] = rsqrtf(1.0f + (float)v);
        }
        __syncthreads();
        if (t == 0) carry += wsum[0] + wsum[1] + wsum[2] + wsum[3];
        __syncthreads();
    }
    if (t == 0) offs[n] = carry;
}

__global__ void scatter_kernel(const int* __restrict__ dst0, int* cur0, int* eid0,
                               const int* __restrict__ dst1, int* cur1, int* eid1) {
    int e = blockIdx.x * blockDim.x + threadIdx.x;
    if (e < NE) {
        int p0 = atomicAdd(&cur0[dst0[e]], 1); eid0[p0] = e;
        int p1 = atomicAdd(&cur1[dst1[e]], 1); eid1[p1] = e;
    }
}

// ---------------------------------------------------------------------------
// Generic W[K,NCOLS] -> fragment-ordered fp16 B-operands (mfma_f32_16x16x32_f16)
// Bf[((nt*KSTEPS+ks)*64+lane)*8+j] = W[ks*32+(lane>>4)*8+j][nt*16+(lane&15)]
// total threads = ntiles*KSTEPS*64.
// ---------------------------------------------------------------------------
__global__ __launch_bounds__(256) void wfrag_kernel(
    const float* __restrict__ W, _Float16* __restrict__ Bf, int KSTEPS, int NCOLS)
{
    int tid = blockIdx.x * 256 + threadIdx.x;
    int l  = tid & 63;
    int ks = (tid >> 6) % KSTEPS;
    int nt = tid / (64 * KSTEPS);
    int n  = nt * 16 + (l & 15);
    int kb = ks * 32 + (l >> 4) * 8;
    half8 v;
    #pragma unroll
    for (int j = 0; j < 8; ++j) v[j] = (_Float16)W[(kb + j) * NCOLS + n];
    *(half8*)&Bf[(size_t)tid * 8] = v;
}

// ---------------------------------------------------------------------------
// PointNet, CSR + MFMA. Block = 256 thr (4 waves), owns 8 nodes, 32-edge chunks.
// Output h written as fp16 row-major [N,512] (consumed by MFMA GEMMs).
// ---------------------------------------------------------------------------
__global__ __launch_bounds__(256) void pointnet_mfma_kernel(
    const float* __restrict__ pos,
    const int* __restrict__ src, const int* __restrict__ dst,
    const int* __restrict__ eid, const int* __restrict__ offs,
    const float* __restrict__ W1, const float* __restrict__ b1,
    const _Float16* __restrict__ Bf, const float* __restrict__ b2,
    _Float16* __restrict__ out, int co)
{
    __shared__ float s_ef[32][8];
    __shared__ int   s_lid[32];
    __shared__ float s_w1[6][256];
    __shared__ float s_b1[256];
    __shared__ float s_b2[256];
    __shared__ _Float16 s_afr[2 * 8 * 64 * 8];   // 16 KB
    __shared__ unsigned int sacc[8][256];        // 8 KB

    const int t = threadIdx.x;
    const int nb = blockIdx.x * 8;

    #pragma unroll
    for (int j = 0; j < 6; ++j) s_w1[j][t] = W1[j * 256 + t];
    s_b1[t] = b1[t];
    s_b2[t] = b2[t];
    #pragma unroll
    for (int ln = 0; ln < 8; ++ln) sacc[ln][t] = 0u;

    const int estart = offs[nb];
    const int eend   = offs[nb + 8];
    __syncthreads();

    const int lane = t & 63;
    const int wv   = t >> 6;
    const int e    = t & 31;
    const int ksid = t >> 5;

    for (int ebase = estart; ebase < eend; ebase += 32) {
        // ---- edge metadata ----
        if (t < 32) {
            int slot = ebase + t;
            int lid = -1;
            float f0 = 0.f, f1 = 0.f, f2 = 0.f, f3 = 0.f, f4 = 0.f, f5 = 0.f;
            if (slot < eend) {
                int ed = eid[slot];
                int s = src[ed], d = dst[ed];
                lid = d - nb;
                float sx = pos[s * 3 + 0], sy = pos[s * 3 + 1], sz = pos[s * 3 + 2];
                float dx = pos[d * 3 + 0], dy = pos[d * 3 + 1], dz = pos[d * 3 + 2];
                f0 = sx; f1 = sy; f2 = sz;
                f3 = sx - dx; f4 = sy - dy; f5 = sz - dz;
            }
            s_lid[t] = lid;
            s_ef[t][0] = f0; s_ef[t][1] = f1; s_ef[t][2] = f2;
            s_ef[t][3] = f3; s_ef[t][4] = f4; s_ef[t][5] = f5;
        }
        __syncthreads();

        // ---- phase 1: hidden -> fp16 A-frags ----
        {
            float f0 = s_ef[e][0], f1 = s_ef[e][1], f2 = s_ef[e][2];
            float f3 = s_ef[e][3], f4 = s_ef[e][4], f5 = s_ef[e][5];
            int mt = e >> 4, m = e & 15;
            #pragma unroll
            for (int q = 0; q < 4; ++q) {
                half8 hv;
                #pragma unroll
                for (int j = 0; j < 8; ++j) {
                    int k = ksid * 32 + q * 8 + j;
                    float h = s_b1[k];
                    h += f0 * s_w1[0][k]; h += f1 * s_w1[1][k]; h += f2 * s_w1[2][k];
                    h += f3 * s_w1[3][k]; h += f4 * s_w1[4][k]; h += f5 * s_w1[5][k];
                    hv[j] = (_Float16)fmaxf(h, 0.f);
                }
                int fl = (mt * 8 + ksid) * 64 + m + 16 * q;
                *(half8*)&s_afr[fl * 8] = hv;
            }
        }
        __syncthreads();

        // ---- phase 2: MFMA ----
        floatx4 acc[2][4];
        #pragma unroll
        for (int mt = 0; mt < 2; ++mt)
            #pragma unroll
            for (int q = 0; q < 4; ++q) acc[mt][q] = (floatx4){0.f, 0.f, 0.f, 0.f};

        #pragma unroll
        for (int ks = 0; ks < 8; ++ks) {
            half8 a0 = *(const half8*)&s_afr[((0 * 8 + ks) * 64 + lane) * 8];
            half8 a1 = *(const half8*)&s_afr[((1 * 8 + ks) * 64 + lane) * 8];
            #pragma unroll
            for (int q = 0; q < 4; ++q) {
                int nt = wv * 4 + q;
                half8 b = *(const half8*)&Bf[(size_t)((nt * 8 + ks) * 64 + lane) * 8];
                acc[0][q] = __builtin_amdgcn_mfma_f32_16x16x32_f16(a0, b, acc[0][q], 0, 0, 0);
                acc[1][q] = __builtin_amdgcn_mfma_f32_16x16x32_f16(a1, b, acc[1][q], 0, 0, 0);
            }
        }

        // ---- epilogue: segmented max into LDS ----
        {
            int rbase = (lane >> 4) * 4;
            #pragma unroll
            for (int q = 0; q < 4; ++q) {
                int ch = (wv * 4 + q) * 16 + (lane & 15);
                float bb = s_b2[ch];
                #pragma unroll
                for (int mt = 0; mt < 2; ++mt) {
                    #pragma unroll
                    for (int r = 0; r < 4; ++r) {
                        int lid = s_lid[mt * 16 + rbase + r];
                        float m = acc[mt][q][r] + bb;
                        if (lid >= 0 && m > 0.f)
                            atomicMax(&sacc[lid][ch], __float_as_uint(m));
                    }
                }
            }
        }
        __syncthreads();
    }

    // ---- final store (fp16 row-major) ----
    #pragma unroll
    for (int ln = 0; ln < 8; ++ln)
        out[(size_t)(nb + ln) * 512 + co + t] = (_Float16)__uint_as_float(sacc[ln][t]);
}

// ---------------------------------------------------------------------------
// MFMA GEMM: C[M,128] = opt_relu(A[M, KSTEPS*32] (fp16, row-major) @ Bfrag + bias)
// block 256 = 4 waves; tile 32 rows x 64 cols; grid (M/32, 2).
// A-frags loaded directly from global (contiguous half8 per lane).
// ---------------------------------------------------------------------------
template <int KSTEPS>
__global__ __launch_bounds__(256) void gemm_mfma_kernel(
    const _Float16* __restrict__ A, const _Float16* __restrict__ Bf,
    const float* __restrict__ bias, float* __restrict__ C, int dorelu)
{
    const int t = threadIdx.x;
    const int lane = t & 63;
    const int wv = t >> 6;
    const int mb = blockIdx.x * 32;
    const int nt = blockIdx.y * 4 + wv;
    const int K = KSTEPS * 32;

    const size_t arow0 = (size_t)(mb + (lane & 15)) * K + (lane >> 4) * 8;
    const size_t arow1 = arow0 + (size_t)16 * K;

    floatx4 acc0 = (floatx4){0.f, 0.f, 0.f, 0.f};
    floatx4 acc1 = (floatx4){0.f, 0.f, 0.f, 0.f};

    #pragma unroll
    for (int ks = 0; ks < KSTEPS; ++ks) {
        half8 a0 = *(const half8*)&A[arow0 + ks * 32];
        half8 a1 = *(const half8*)&A[arow1 + ks * 32];
        half8 b  = *(const half8*)&Bf[(size_t)((nt * KSTEPS + ks) * 64 + lane) * 8];
        acc0 = __builtin_amdgcn_mfma_f32_16x16x32_f16(a0, b, acc0, 0, 0, 0);
        acc1 = __builtin_amdgcn_mfma_f32_16x16x32_f16(a1, b, acc1, 0, 0, 0);
    }

    const int col = nt * 16 + (lane & 15);
    const int rb  = (lane >> 4) * 4;
    const float bb = bias ? bias[col] : 0.f;
    #pragma unroll
    for (int r = 0; r < 4; ++r) {
        float v0 = acc0[r] + bb;
        float v1 = acc1[r] + bb;
        if (dorelu) { v0 = fmaxf(v0, 0.f); v1 = fmaxf(v1, 0.f); }
        C[(size_t)(mb + rb + r) * 128 + col]      = v0;
        C[(size_t)(mb + 16 + rb + r) * 128 + col] = v1;
    }
}

// ---------------------------------------------------------------------------
// GCN gather, wave-per-node: lane j's (src, norm) broadcast via shfl;
// each lane accumulates 2 channels (float2, 512B coalesced per edge).
// Fuses self term + bias + relu; writes h2 as fp16 [N,256].
// ---------------------------------------------------------------------------
__global__ __launch_bounds__(256) void gcn_gather_kernel(
    const int* __restrict__ src, const int* __restrict__ eid,
    const int* __restrict__ offs, const float* __restrict__ dinv,
    const float* __restrict__ xw, const float* __restrict__ b,
    _Float16* __restrict__ h2, int co)
{
    const int t = threadIdx.x;
    const int lane = t & 63;
    const int i = blockIdx.x * 4 + (t >> 6);
    const int e0 = offs[i], e1 = offs[i + 1];
    const float di = dinv[i];

    float ax = 0.f, ay = 0.f;
    for (int base = e0; base < e1; base += 64) {
        int k = base + lane;
        int s = 0; float nr = 0.f;
        if (k < e1) {
            int e = eid[k];
            s = src[e];
            nr = dinv[s];
        }
        int m = min(64, e1 - base);
        for (int j = 0; j < m; ++j) {
            int   sj = __shfl(s, j);
            float nj = __shfl(nr, j);
            float2 v = *(const float2*)&xw[(size_t)sj * 128 + 2 * lane];
            ax += v.x * nj;
            ay += v.y * nj;
        }
    }

    float2 xi = *(const float2*)&xw[(size_t)i * 128 + 2 * lane];
    float vx = ax * di + xi.x * di * di + b[2 * lane];
    float vy = ay * di + xi.y * di * di + b[2 * lane + 1];
    half2v o;
    o[0] = (_Float16)fmaxf(vx, 0.f);
    o[1] = (_Float16)fmaxf(vy, 0.f);
    *(half2v*)&h2[(size_t)i * 256 + co + 2 * lane] = o;
}

// ---------------------------------------------------------------------------
// Final classifier: out[3] = z_flat @ cls_W + cls_b  (out pre-zeroed)
// ---------------------------------------------------------------------------
__global__ __launch_bounds__(256) void classifier_kernel(
    const float* __restrict__ z, const float* __restrict__ clsW,
    const float* __restrict__ clsb, float* __restrict__ out)
{
    float a0 = 0.f, a1 = 0.f, a2 = 0.f;
    const int total = N_NODES * 128;
    for (int i = blockIdx.x * blockDim.x + threadIdx.x; i < total;
         i += gridDim.x * blockDim.x) {
        float v = z[i];
        a0 += v * clsW[(size_t)i * 3 + 0];
        a1 += v * clsW[(size_t)i * 3 + 1];
        a2 += v * clsW[(size_t)i * 3 + 2];
    }
    #pragma unroll
    for (int off = 32; off > 0; off >>= 1) {
        a0 += __shfl_down(a0, off);
        a1 += __shfl_down(a1, off);
        a2 += __shfl_down(a2, off);
    }
    __shared__ float sred[12];
    int w = threadIdx.x >> 6;
    if ((threadIdx.x & 63) == 0) { sred[w * 3] = a0; sred[w * 3 + 1] = a1; sred[w * 3 + 2] = a2; }
    __syncthreads();
    if (threadIdx.x == 0) {
        float r0 = 0.f, r1 = 0.f, r2 = 0.f;
        #pragma unroll
        for (int q = 0; q < 4; ++q) { r0 += sred[q * 3]; r1 += sred[q * 3 + 1]; r2 += sred[q * 3 + 2]; }
        atomicAdd(&out[0], r0); atomicAdd(&out[1], r1); atomicAdd(&out[2], r2);
    }
    if (blockIdx.x == 0 && threadIdx.x < 3) atomicAdd(&out[threadIdx.x], clsb[threadIdx.x]);
}

// ---------------------------------------------------------------------------
extern "C" void kernel_launch(void* const* d_in, const int* in_sizes, int n_in,
                              void* d_out, int out_size, void* d_ws, size_t ws_size,
                              hipStream_t stream) {
    const float* pos0 = (const float*)d_in[0];
    const float* pos1 = (const float*)d_in[1];
    const int*   ei0  = (const int*)d_in[2];
    const int*   ei1  = (const int*)d_in[3];
    const float* p0W1 = (const float*)d_in[6];
    const float* p0b1 = (const float*)d_in[7];
    const float* p0W2 = (const float*)d_in[8];
    const float* p0b2 = (const float*)d_in[9];
    const float* p1W1 = (const float*)d_in[10];
    const float* p1b1 = (const float*)d_in[11];
    const float* p1W2 = (const float*)d_in[12];
    const float* p1b2 = (const float*)d_in[13];
    const float* g0W  = (const float*)d_in[14];
    const float* g0b  = (const float*)d_in[15];
    const float* g1W  = (const float*)d_in[16];
    const float* g1b  = (const float*)d_in[17];
    const float* c3W  = (const float*)d_in[18];
    const float* c3b  = (const float*)d_in[19];
    const float* clsW = (const float*)d_in[20];
    const float* clsb = (const float*)d_in[21];

    const int* s0 = ei0;       const int* d0 = ei0 + NE;
    const int* s1 = ei1;       const int* d1 = ei1 + NE;

    float* ws = (float*)d_ws;
    _Float16* h   = (_Float16*)ws;               // [N,512] fp16 = 5,120,000 f
    float* xw0    = ws + 5120000;                // [N,128] fp32
    float* xw1    = ws + 7680000;
    _Float16* h2  = (_Float16*)(ws + 10240000);  // [N,256] fp16 = 2,560,000 f
    float* z      = ws + 12800000;               // [N,128] fp32
    int*   cnt0  = (int*)(ws + 15360000);        // [N]
    int*   cnt1  = (int*)(ws + 15380000);
    int*   cur0  = (int*)(ws + 15400000);
    int*   cur1  = (int*)(ws + 15420000);
    int*   offs0 = (int*)(ws + 15440000);        // [N+1]
    int*   offs1 = (int*)(ws + 15460004);        // [N+1]
    int*   eid0  = (int*)(ws + 15480008);        // [E]
    int*   eid1  = (int*)(ws + 15880008);
    float* dinv0 = ws + 16280008;                // [N]
    float* dinv1 = ws + 16300008;
    _Float16* w2f0 = (_Float16*)(ws + 16320008); // 65536 halfs
    _Float16* w2f1 = (_Float16*)(ws + 16352776);
    _Float16* gwf0 = (_Float16*)(ws + 16385544); // 65536 halfs
    _Float16* gwf1 = (_Float16*)(ws + 16418312);
    _Float16* c3f  = (_Float16*)(ws + 16451080); // 32768 halfs

    hipMemsetAsync(cnt0, 0, (size_t)2 * N_NODES * sizeof(int), stream);
    hipMemsetAsync(d_out, 0, 3 * sizeof(float), stream);

    // CSR build (by dst) + weight fragment conversion
    count_kernel<<<(NE + 255) / 256, 256, 0, stream>>>(d0, cnt0, d1, cnt1);
    wfrag_kernel<<<32, 256, 0, stream>>>(p0W2, w2f0, 8, 256);
    wfrag_kernel<<<32, 256, 0, stream>>>(p1W2, w2f1, 8, 256);
    wfrag_kernel<<<32, 256, 0, stream>>>(g0W, gwf0, 16, 128);
    wfrag_kernel<<<32, 256, 0, stream>>>(g1W, gwf1, 16, 128);
    wfrag_kernel<<<16, 256, 0, stream>>>(c3W, c3f, 8, 128);
    scan_kernel<<<1, 256, 0, stream>>>(cnt0, offs0, cur0, dinv0, N_NODES);
    scan_kernel<<<1, 256, 0, stream>>>(cnt1, offs1, cur1, dinv1, N_NODES);
    scatter_kernel<<<(NE + 255) / 256, 256, 0, stream>>>(d0, cur0, eid0, d1, cur1, eid1);

    // PointNet layers -> h[N, 0:256], h[N, 256:512] (fp16)
    pointnet_mfma_kernel<<<N_NODES / 8, 256, 0, stream>>>(
        pos0, s0, d0, eid0, offs0, p0W1, p0b1, w2f0, p0b2, h, 0);
    pointnet_mfma_kernel<<<N_NODES / 8, 256, 0, stream>>>(
        pos1, s1, d1, eid1, offs1, p1W1, p1b1, w2f1, p1b2, h, 256);

    // xw = h @ gW (fp16 MFMA, K=512) -> fp32
    gemm_mfma_kernel<16><<<dim3(N_NODES / 32, 2), 256, 0, stream>>>(h, gwf0, nullptr, xw0, 0);
    gemm_mfma_kernel<16><<<dim3(N_NODES / 32, 2), 256, 0, stream>>>(h, gwf1, nullptr, xw1, 0);

    // fused GCN aggregation (wave-per-node gather) -> h2 [N,256] fp16
    gcn_gather_kernel<<<N_NODES / 4, 256, 0, stream>>>(s0, eid0, offs0, dinv0, xw0, g0b, h2, 0);
    gcn_gather_kernel<<<N_NODES / 4, 256, 0, stream>>>(s1, eid1, offs1, dinv1, xw1, g1b, h2, 128);

    // z = relu(h2 @ c3W + c3b) (fp16 MFMA, K=256) -> fp32
    gemm_mfma_kernel<8><<<dim3(N_NODES / 32, 2), 256, 0, stream>>>(h2, c3f, c3b, z, 1);

    // out = z_flat @ clsW + clsb
    classifier_kernel<<<2048, 256, 0, stream>>>(z, clsW, clsb, (float*)d_out);
}